// Round 17
// baseline (627.865 us; speedup 1.0000x reference)
//
#include <hip/hip_runtime.h>

#define TT 1024
#define NB 32
#define NJ 128
#define NI 512
#define KD 16
#define LVL 1048576   // shorts per level in WF (512*2048)

typedef short bf16x8 __attribute__((ext_vector_type(8)));
typedef float floatx4 __attribute__((ext_vector_type(4)));

struct S3 { short h, m, l; };

// 3-way bf16 truncation split: v = h + m + l + O(2^-24 v). Residuals exact.
__device__ __forceinline__ S3 split3(float v) {
    S3 o;
    unsigned hb = __float_as_uint(v) & 0xFFFF0000u;
    float hf = __uint_as_float(hb);
    float r1 = v - hf;
    unsigned mb = __float_as_uint(r1) & 0xFFFF0000u;
    float mf = __uint_as_float(mb);
    float r2 = r1 - mf;
    unsigned lb = __float_as_uint(r2) & 0xFFFF0000u;
    o.h = (short)(hb >> 16);
    o.m = (short)(mb >> 16);
    o.l = (short)(lb >> 16);
    return o;
}

// ---------------- DCLS: W in 3-level bf16 MFMA B-frag layout [R10-proven] ----------------
__global__ __launch_bounds__(256) void dcls_kern(const float* __restrict__ w,
                                                 const float* __restrict__ P,
                                                 short* __restrict__ WF) {
    int idx = blockIdx.x * 256 + threadIdx.x;   // idx = i*128 + j
    int j = idx & (NJ - 1);
    int i = idx >> 7;
    float wv = w[i * NJ + j];
    float c  = P[i * NJ + j] + (float)(KD / 2);
    float g[KD];
    float s = 0.f;
#pragma unroll
    for (int k = 0; k < KD; ++k) {
        float u = (float)k - c;
        g[k] = expf(-2.0f * u * u);
        s += g[k];
    }
    float inv = wv / (s + 1e-7f);
    size_t base = (size_t)(i >> 4) * 32768 + (size_t)(j >> 3) * 128 + (i & 15) * 8 + (j & 7);
#pragma unroll
    for (int d = 0; d < KD; ++d) {
        S3 sp = split3(g[(KD - 1) - d] * inv);   // conv flip
        size_t off = base + (size_t)d * 2048;
        WF[off]           = sp.h;
        WF[off + LVL]     = sp.m;
        WF[off + 2 * LVL] = sp.l;
    }
}

// ---------------- MFMA conv: y[t,b,i] = sum_{d,j} W[i][d*128+j] * x[t-d,b,j] ----
// R15 base (256t x 256i, 8 waves, 1 block/CU) + INTERLEAVED PHASES + LDS dbuf +
// single barrier per K-step: the 4 MFMA quadrants (48 MFMA each) are separated
// by the 2 stage-row slices (tile k+1 -> other buffer) and the W/X prefetches,
// so the matrix pipe is never starved by a monolithic stage phase.
// LDS (dynamic 104KB): PA dbuf 2x32KB [Ah|Am] swizzled; PL dbuf 2x20KB packed
// 40-short rows (pad = conflict-free). 6 MFMA products.
__global__ __launch_bounds__(512, 2) void conv_mfma(const float* __restrict__ x,
                                                    const short* __restrict__ WF,
                                                    float* __restrict__ y) {
    extern __shared__ __align__(16) char lds[];
    char* PAb[2]; char* PLb[2];
    PAb[0] = lds;            PAb[1] = lds + 32768;
    PLb[0] = lds + 65536;    PLb[1] = lds + 86016;   // PL rows: 40 shorts (80B)

    const int t0 = blockIdx.x * 256;
    const int i0 = blockIdx.y * 256;
    const int b  = blockIdx.z;
    const int tid = threadIdx.x;

    const int ch   = tid & 3;            // staging: 4 chunks x 8 floats = 32 cols
    const int rw   = tid >> 2;           // 0..127; thread stages rows rw, rw+128
    const int l    = tid & 63;
    const int wv   = tid >> 6;           // wave 0..7
    const int lr16 = l & 15;
    const int kb   = l >> 4;             // k-octet 0..3
    const int wm   = wv >> 2;            // 0..1 -> 128 t-rows
    const int wn   = wv & 3;             // 0..3 -> 64 i-cols

    const short* pnf[4];
#pragma unroll
    for (int nf = 0; nf < 4; ++nf) {
        int ig = (i0 + wn * 64 + nf * 16) >> 4;
        pnf[nf] = WF + (size_t)ig * 32768 + l * 8;
    }

    floatx4 acc[8][4];
#pragma unroll
    for (int mf = 0; mf < 8; ++mf)
#pragma unroll
        for (int nf = 0; nf < 4; ++nf)
#pragma unroll
            for (int e = 0; e < 4; ++e) acc[mf][nf][e] = 0.f;

    float4 ga[2][2];
    bf16x8 W0h[4], W0m[4], W0l[4], W1h[4], W1m[4], W1l[4];

#define LOADW(K, H, M, L_) {                                                    \
    int koff = ((((K) >> 2) * 16 + ((K) & 3) * 4)) * 128;                       \
    _Pragma("unroll") for (int nf = 0; nf < 4; ++nf) {                          \
        const short* p = pnf[nf] + koff;                                        \
        H[nf]  = *(const bf16x8*)(p);                                           \
        M[nf]  = *(const bf16x8*)(p + LVL);                                     \
        L_[nf] = *(const bf16x8*)(p + 2 * LVL); } }

#define LOADX(K) {                                                              \
    int dn = (K) >> 2, j0n = ((K) & 3) << 5;                                    \
    _Pragma("unroll") for (int s = 0; s < 2; ++s) {                             \
        int t = t0 + rw + s * 128 - dn;                                         \
        float4 z4 = make_float4(0.f, 0.f, 0.f, 0.f);                            \
        ga[s][0] = z4; ga[s][1] = z4;                                           \
        if (t >= 0) {                                                           \
            const float* ax = x + ((size_t)t * NB + b) * NJ + j0n + ch * 8;     \
            ga[s][0] = *(const float4*)ax;                                      \
            ga[s][1] = *(const float4*)(ax + 4); } } }

#define STAGE_ROW(S, BA, BL) {                                                  \
    int r = rw + (S) * 128;                                                     \
    int key = r & 7;                                                            \
    char* rowA = (BA) + r * 128;                                                \
    char* rowL = (BL) + r * 80;                                                 \
    S3 a0 = split3(ga[S][0].x), a1 = split3(ga[S][0].y),                        \
       a2 = split3(ga[S][0].z), a3 = split3(ga[S][0].w),                        \
       a4 = split3(ga[S][1].x), a5 = split3(ga[S][1].y),                        \
       a6 = split3(ga[S][1].z), a7 = split3(ga[S][1].w);                        \
    bf16x8 h8, m8, l8;                                                          \
    h8[0]=a0.h; h8[1]=a1.h; h8[2]=a2.h; h8[3]=a3.h;                             \
    h8[4]=a4.h; h8[5]=a5.h; h8[6]=a6.h; h8[7]=a7.h;                             \
    m8[0]=a0.m; m8[1]=a1.m; m8[2]=a2.m; m8[3]=a3.m;                             \
    m8[4]=a4.m; m8[5]=a5.m; m8[6]=a6.m; m8[7]=a7.m;                             \
    l8[0]=a0.l; l8[1]=a1.l; l8[2]=a2.l; l8[3]=a3.l;                             \
    l8[4]=a4.l; l8[5]=a5.l; l8[6]=a6.l; l8[7]=a7.l;                             \
    *(bf16x8*)(rowA + ((ch ^ key) * 16))       = h8;                            \
    *(bf16x8*)(rowA + (((ch + 4) ^ key) * 16)) = m8;                            \
    *(bf16x8*)(rowL + ch * 16)                 = l8; }

#define DOQUAD(Q, BA, BL, WH, WM, WL) {                                         \
    _Pragma("unroll") for (int mf = 2 * (Q); mf < 2 * (Q) + 2; ++mf) {          \
        int row = wm * 128 + mf * 16 + lr16;                                    \
        int key = row & 7;                                                      \
        const char* rowA = (const char*)(BA) + row * 128;                       \
        const char* rowL = (const char*)(BL) + row * 80;                        \
        bf16x8 ah = *(const bf16x8*)(rowA + ((kb ^ key) * 16));                 \
        bf16x8 am = *(const bf16x8*)(rowA + (((kb + 4) ^ key) * 16));           \
        bf16x8 al = *(const bf16x8*)(rowL + kb * 16);                           \
        _Pragma("unroll") for (int nf = 0; nf < 4; ++nf)                        \
            acc[mf][nf] = __builtin_amdgcn_mfma_f32_16x16x32_bf16(ah, WH[nf], acc[mf][nf], 0, 0, 0); \
        _Pragma("unroll") for (int nf = 0; nf < 4; ++nf)                        \
            acc[mf][nf] = __builtin_amdgcn_mfma_f32_16x16x32_bf16(ah, WM[nf], acc[mf][nf], 0, 0, 0); \
        _Pragma("unroll") for (int nf = 0; nf < 4; ++nf)                        \
            acc[mf][nf] = __builtin_amdgcn_mfma_f32_16x16x32_bf16(am, WH[nf], acc[mf][nf], 0, 0, 0); \
        _Pragma("unroll") for (int nf = 0; nf < 4; ++nf)                        \
            acc[mf][nf] = __builtin_amdgcn_mfma_f32_16x16x32_bf16(am, WM[nf], acc[mf][nf], 0, 0, 0); \
        _Pragma("unroll") for (int nf = 0; nf < 4; ++nf)                        \
            acc[mf][nf] = __builtin_amdgcn_mfma_f32_16x16x32_bf16(ah, WL[nf], acc[mf][nf], 0, 0, 0); \
        _Pragma("unroll") for (int nf = 0; nf < 4; ++nf)                        \
            acc[mf][nf] = __builtin_amdgcn_mfma_f32_16x16x32_bf16(al, WH[nf], acc[mf][nf], 0, 0, 0); \
    } }

// One K-step: compute tile K from (BC_A,BC_L,WC*), stage tile K+1 into (BN_A,BN_L),
// prefetch x(K+2) and W(K+1) between quadrants; ONE barrier.
#define STEP(K, BC_A, BC_L, BN_A, BN_L, WCh, WCm, WCl, WNh, WNm, WNl) {         \
    DOQUAD(0, BC_A, BC_L, WCh, WCm, WCl)                                        \
    if ((K) + 1 < 64) { STAGE_ROW(0, BN_A, BN_L) }                              \
    DOQUAD(1, BC_A, BC_L, WCh, WCm, WCl)                                        \
    if ((K) + 1 < 64) { LOADW((K) + 1, WNh, WNm, WNl) }                         \
    DOQUAD(2, BC_A, BC_L, WCh, WCm, WCl)                                        \
    if ((K) + 1 < 64) { STAGE_ROW(1, BN_A, BN_L) }                              \
    if ((K) + 2 < 64) { LOADX((K) + 2) }                                        \
    DOQUAD(3, BC_A, BC_L, WCh, WCm, WCl)                                        \
    __syncthreads(); }

    // prologue: stage tile 0 -> buf0; ga <- tile 1; W(0)
    LOADX(0)
    STAGE_ROW(0, PAb[0], PLb[0])
    STAGE_ROW(1, PAb[0], PLb[0])
    LOADX(1)
    LOADW(0, W0h, W0m, W0l)
    __syncthreads();

#pragma unroll 1
    for (int kk = 0; kk < 64; kk += 2) {
        STEP(kk,     PAb[0], PLb[0], PAb[1], PLb[1], W0h, W0m, W0l, W1h, W1m, W1l)
        STEP(kk + 1, PAb[1], PLb[1], PAb[0], PLb[0], W1h, W1m, W1l, W0h, W0m, W0l)
    }
#undef LOADW
#undef LOADX
#undef STAGE_ROW
#undef DOQUAD
#undef STEP

    // ---- epilogue: C/D layout col=lane&15, row=(lane>>4)*4+reg [m89-verified] ----
#pragma unroll
    for (int mf = 0; mf < 8; ++mf)
#pragma unroll
        for (int nf = 0; nf < 4; ++nf) {
            int ic = i0 + wn * 64 + nf * 16 + lr16;
#pragma unroll
            for (int q = 0; q < 4; ++q) {
                int t = t0 + wm * 128 + mf * 16 + kb * 4 + q;
                y[((size_t)t * NB + b) * NI + ic] = acc[mf][nf][q];
            }
        }
}

// ---------------- BN stats pass 1: per-block partial sum/sumsq over 128 rows ----
__global__ __launch_bounds__(256) void red1(const float* __restrict__ y,
                                            float* __restrict__ part) {
    int r0 = blockIdx.x * 128;
    int c  = threadIdx.x;
    float s0 = 0.f, q0 = 0.f, s1 = 0.f, q1 = 0.f;
#pragma unroll 4
    for (int r = 0; r < 128; ++r) {
        float v0 = y[(size_t)(r0 + r) * NI + c];
        float v1 = y[(size_t)(r0 + r) * NI + c + 256];
        s0 += v0; q0 = fmaf(v0, v0, q0);
        s1 += v1; q1 = fmaf(v1, v1, q1);
    }
    part[blockIdx.x * NI + c]            = s0;
    part[blockIdx.x * NI + c + 256]      = s1;
    part[256 * NI + blockIdx.x * NI + c]       = q0;
    part[256 * NI + blockIdx.x * NI + c + 256] = q1;
}

// ---------------- BN stats pass 2: combine partials (double), emit scale/bias ----
__global__ __launch_bounds__(512) void red2(const float* __restrict__ part,
                                            const float* __restrict__ gamma,
                                            const float* __restrict__ bbeta,
                                            float* __restrict__ sb) {
    int c = threadIdx.x;
    double s = 0.0, q = 0.0;
#pragma unroll 8
    for (int p = 0; p < 256; ++p) {
        s += (double)part[p * NI + c];
        q += (double)part[256 * NI + p * NI + c];
    }
    double mean = s / 32768.0;
    double var  = q / 32768.0 - mean * mean;
    double scale = (double)gamma[c] / sqrt(var + 1e-5);
    sb[c]      = (float)scale;
    sb[NI + c] = (float)((double)bbeta[c] - mean * scale);
}

// ---------------- soft-reset LIF scan, in-place over y (=d_out) ----------------
__global__ __launch_bounds__(64) void scan_kern(float* __restrict__ y,
                                                const float* __restrict__ sb,
                                                const float* __restrict__ beta,
                                                const float* __restrict__ U0) {
    int g = blockIdx.x * 64 + threadIdx.x;   // 0..16383 = b*512 + i
    int i = g & (NI - 1);
    float scale = sb[i];
    float bias  = sb[NI + i];
    float bet = beta[i];
    float omb = 1.f - bet;
    float u = U0[g];
    float s = 0.f;
    float* yp = y + g;

    float A[32], Bv[32];
#pragma unroll
    for (int r = 0; r < 32; ++r) A[r] = yp[(size_t)r * 16384];

    for (int t0 = 0; t0 < TT; t0 += 64) {
#pragma unroll
        for (int r = 0; r < 32; ++r) Bv[r] = yp[(size_t)(t0 + 32 + r) * 16384];
#pragma unroll
        for (int r = 0; r < 32; ++r) {
            float z = fmaf(A[r], scale, bias);
            u = fmaf(bet, u - s, omb * z);
            s = (u >= 1.f) ? 1.f : 0.f;
            yp[(size_t)(t0 + r) * 16384] = s;
        }
        if (t0 + 64 < TT) {
#pragma unroll
            for (int r = 0; r < 32; ++r) A[r] = yp[(size_t)(t0 + 64 + r) * 16384];
        }
#pragma unroll
        for (int r = 0; r < 32; ++r) {
            float z = fmaf(Bv[r], scale, bias);
            u = fmaf(bet, u - s, omb * z);
            s = (u >= 1.f) ? 1.f : 0.f;
            yp[(size_t)(t0 + 32 + r) * 16384] = s;
        }
    }
}

extern "C" void kernel_launch(void* const* d_in, const int* in_sizes, int n_in,
                              void* d_out, int out_size, void* d_ws, size_t ws_size,
                              hipStream_t stream) {
    const float* x       = (const float*)d_in[0];
    const float* delay_w = (const float*)d_in[1];
    const float* delay_P = (const float*)d_in[2];
    const float* beta    = (const float*)d_in[3];
    const float* bn_g    = (const float*)d_in[4];
    const float* bn_b    = (const float*)d_in[5];
    const float* U0      = (const float*)d_in[6];
    float* y = (float*)d_out;

    // ws layout (6 MiB total, R10-proven): WF occupies [0, 6 MiB). part/sb ALIAS
    // WF's space — safe because kernels serialize on the stream and every buffer
    // is fully rewritten before each read -> deterministic under graph replay.
    short* WF   = (short*)d_ws;
    float* part = (float*)d_ws;
    float* sb   = (float*)d_ws + 2 * 256 * NI;

    (void)hipFuncSetAttribute((const void*)conv_mfma,
                              hipFuncAttributeMaxDynamicSharedMemorySize, 106496);

    dcls_kern<<<dim3(NI * NJ / 256), dim3(256), 0, stream>>>(delay_w, delay_P, WF);
    conv_mfma<<<dim3(TT / 256, NI / 256, NB), dim3(512), 106496, stream>>>(x, WF, y);
    red1<<<dim3(TT * NB / 128), dim3(256), 0, stream>>>(y, part);
    red2<<<dim3(1), dim3(512), 0, stream>>>(part, bn_g, bn_b, sb);
    scan_kern<<<dim3(NB * NI / 64), dim3(64), 0, stream>>>(y, sb, beta, U0);
}

// Round 18
// 383.980 us; speedup vs baseline: 1.6352x; 1.6352x over previous
//
#include <hip/hip_runtime.h>

#define TT 1024
#define NB 32
#define NJ 128
#define NI 512
#define KD 16
#define LVL 1048576   // shorts per level in WF (512*2048)

typedef short bf16x8 __attribute__((ext_vector_type(8)));
typedef float floatx16 __attribute__((ext_vector_type(16)));

struct S3 { short h, m, l; };

// 3-way bf16 truncation split: v = h + m + l + O(2^-24 v). Residuals exact.
__device__ __forceinline__ S3 split3(float v) {
    S3 o;
    unsigned hb = __float_as_uint(v) & 0xFFFF0000u;
    float hf = __uint_as_float(hb);
    float r1 = v - hf;
    unsigned mb = __float_as_uint(r1) & 0xFFFF0000u;
    float mf = __uint_as_float(mb);
    float r2 = r1 - mf;
    unsigned lb = __float_as_uint(r2) & 0xFFFF0000u;
    o.h = (short)(hb >> 16);
    o.m = (short)(mb >> 16);
    o.l = (short)(lb >> 16);
    return o;
}

// ---------------- DCLS: W in 3-level bf16 32x32x16-B-frag layout ----------------
// k = d*128 + j. Frag convention (32x32x16): col i = lane&31, k = (lane>>5)*8 + e.
// WF[lvl][ig=i>>5][kp=k>>4][lane=((k>>3)&1)*32 + (i&31)][e=k&7]: a wave's B-frag
// for (ig, kp) is one contiguous 1KB block = 1 dwordx4 per lane.
// Trace: (i=17,d=2,j=3) -> k=259, kp=16, lane=17, e=3 -> off 8331 (matches reader).
__global__ __launch_bounds__(256) void dcls_kern(const float* __restrict__ w,
                                                 const float* __restrict__ P,
                                                 short* __restrict__ WF) {
    int idx = blockIdx.x * 256 + threadIdx.x;   // idx = i*128 + j
    int j = idx & (NJ - 1);
    int i = idx >> 7;
    float wv = w[i * NJ + j];
    float c  = P[i * NJ + j] + (float)(KD / 2);
    float g[KD];
    float s = 0.f;
#pragma unroll
    for (int k = 0; k < KD; ++k) {
        float u = (float)k - c;
        g[k] = expf(-2.0f * u * u);
        s += g[k];
    }
    float inv = wv / (s + 1e-7f);
    int lane = ((j >> 3) & 1) * 32 + (i & 31);
    size_t base = (size_t)(i >> 5) * 65536 + (size_t)(j >> 4) * 512 + lane * 8 + (j & 7);
#pragma unroll
    for (int d = 0; d < KD; ++d) {
        S3 sp = split3(g[(KD - 1) - d] * inv);   // conv flip
        size_t off = base + (size_t)d * 4096;    // d advances kp by 8 -> 8*512 shorts
        WF[off]           = sp.h;
        WF[off + LVL]     = sp.m;
        WF[off + 2 * LVL] = sp.l;
    }
}

// ---------------- MFMA conv: y[t,b,i] = sum_{d,j} W[i][d*128+j] * x[t-d,b,j] ----
// R15 structure exactly (256t x 256i, 8 waves 2x4, BK=32, 1 block/CU, XOR-swizzled
// A staging, W from global frag layout) with mfma_f32_32x32x16_bf16:
// wave-tile 128x64 = 4 mr x 2 nf tiles of 32x32, 2 k-slices -> 96 MFMA/wave/K-step
// (was 192 of 16x16) at the 15%-faster 32x32 rate. 6 products: hh+hm+mh+mm+hl+lh.
__global__ __launch_bounds__(512, 2) void conv_mfma(const float* __restrict__ x,
                                                    const short* __restrict__ WF,
                                                    float* __restrict__ y) {
    __shared__ __align__(16) short PA[256][64];   // [Ah | Am], 8x16B chunks/row (32 KB)
    __shared__ __align__(16) short PL[256][64];   // [Al | --]             (32 KB)

    const int t0 = blockIdx.x * 256;
    const int i0 = blockIdx.y * 256;
    const int b  = blockIdx.z;
    const int tid = threadIdx.x;

    const int ch   = tid & 3;            // staging: 4 chunks x 8 floats = 32 cols
    const int rw   = tid >> 2;           // 0..127; thread stages rows rw, rw+128
    const int l    = tid & 63;
    const int wv   = tid >> 6;           // wave 0..7
    const int l31  = l & 31;             // frag row/col within 32
    const int lhi  = l >> 5;             // k-octet half 0..1
    const int wm   = wv >> 2;            // 0..1 -> 128 t-rows
    const int wn   = wv & 3;             // 0..3 -> 64 i-cols

    const short* pnf[2];
#pragma unroll
    for (int nf = 0; nf < 2; ++nf) {
        int ig = (i0 + wn * 64 + nf * 32) >> 5;
        pnf[nf] = WF + (size_t)ig * 65536 + l * 8;
    }

    floatx16 acc[4][2];
#pragma unroll
    for (int mr = 0; mr < 4; ++mr)
#pragma unroll
        for (int nf = 0; nf < 2; ++nf)
#pragma unroll
            for (int e = 0; e < 16; ++e) acc[mr][nf][e] = 0.f;

    float4 ga[2][2];
    bf16x8 Bh[2][2], Bm[2][2], Bl[2][2];   // [nf][ks]

#define LOADW(K) {                                                              \
    _Pragma("unroll") for (int nf = 0; nf < 2; ++nf)                            \
    _Pragma("unroll") for (int ks = 0; ks < 2; ++ks) {                          \
        const short* p = pnf[nf] + ((size_t)((K) * 2 + ks)) * 512;              \
        Bh[nf][ks] = *(const bf16x8*)(p);                                       \
        Bm[nf][ks] = *(const bf16x8*)(p + LVL);                                 \
        Bl[nf][ks] = *(const bf16x8*)(p + 2 * LVL); } }

#define LOADX(K) {                                                              \
    int dn = (K) >> 2, j0n = ((K) & 3) << 5;                                    \
    _Pragma("unroll") for (int s = 0; s < 2; ++s) {                             \
        int t = t0 + rw + s * 128 - dn;                                         \
        float4 z4 = make_float4(0.f, 0.f, 0.f, 0.f);                            \
        ga[s][0] = z4; ga[s][1] = z4;                                           \
        if (t >= 0) {                                                           \
            const float* ax = x + ((size_t)t * NB + b) * NJ + j0n + ch * 8;     \
            ga[s][0] = *(const float4*)ax;                                      \
            ga[s][1] = *(const float4*)(ax + 4); } } }

#define STAGEW() {                                                              \
    _Pragma("unroll") for (int s = 0; s < 2; ++s) {                             \
        int r = rw + s * 128;                                                   \
        int key = r & 7;                                                        \
        char* rowA = (char*)PA + r * 128;                                       \
        char* rowL = (char*)PL + r * 128;                                       \
        S3 a0 = split3(ga[s][0].x), a1 = split3(ga[s][0].y),                    \
           a2 = split3(ga[s][0].z), a3 = split3(ga[s][0].w),                    \
           a4 = split3(ga[s][1].x), a5 = split3(ga[s][1].y),                    \
           a6 = split3(ga[s][1].z), a7 = split3(ga[s][1].w);                    \
        bf16x8 h8, m8, l8;                                                      \
        h8[0]=a0.h; h8[1]=a1.h; h8[2]=a2.h; h8[3]=a3.h;                         \
        h8[4]=a4.h; h8[5]=a5.h; h8[6]=a6.h; h8[7]=a7.h;                         \
        m8[0]=a0.m; m8[1]=a1.m; m8[2]=a2.m; m8[3]=a3.m;                         \
        m8[4]=a4.m; m8[5]=a5.m; m8[6]=a6.m; m8[7]=a7.m;                         \
        l8[0]=a0.l; l8[1]=a1.l; l8[2]=a2.l; l8[3]=a3.l;                         \
        l8[4]=a4.l; l8[5]=a5.l; l8[6]=a6.l; l8[7]=a7.l;                         \
        *(bf16x8*)(rowA + ((ch ^ key) * 16))       = h8;                        \
        *(bf16x8*)(rowA + (((ch + 4) ^ key) * 16)) = m8;                        \
        *(bf16x8*)(rowL + ((ch ^ key) * 16))       = l8; } }

#define DOMFMA() {                                                              \
    _Pragma("unroll") for (int mr = 0; mr < 4; ++mr) {                          \
        int row = wm * 128 + mr * 32 + l31;                                     \
        int key = row & 7;                                                      \
        const char* rowA = (const char*)PA + row * 128;                         \
        const char* rowL = (const char*)PL + row * 128;                         \
        _Pragma("unroll") for (int ks = 0; ks < 2; ++ks) {                      \
            int oct = ks * 2 + lhi;                                             \
            bf16x8 ah = *(const bf16x8*)(rowA + ((oct ^ key) * 16));            \
            bf16x8 am = *(const bf16x8*)(rowA + (((oct + 4) ^ key) * 16));      \
            bf16x8 al = *(const bf16x8*)(rowL + ((oct ^ key) * 16));            \
            _Pragma("unroll") for (int nf = 0; nf < 2; ++nf) {                  \
                acc[mr][nf] = __builtin_amdgcn_mfma_f32_32x32x16_bf16(ah, Bh[nf][ks], acc[mr][nf], 0, 0, 0); \
                acc[mr][nf] = __builtin_amdgcn_mfma_f32_32x32x16_bf16(ah, Bm[nf][ks], acc[mr][nf], 0, 0, 0); \
                acc[mr][nf] = __builtin_amdgcn_mfma_f32_32x32x16_bf16(am, Bh[nf][ks], acc[mr][nf], 0, 0, 0); \
                acc[mr][nf] = __builtin_amdgcn_mfma_f32_32x32x16_bf16(am, Bm[nf][ks], acc[mr][nf], 0, 0, 0); \
                acc[mr][nf] = __builtin_amdgcn_mfma_f32_32x32x16_bf16(ah, Bl[nf][ks], acc[mr][nf], 0, 0, 0); \
                acc[mr][nf] = __builtin_amdgcn_mfma_f32_32x32x16_bf16(al, Bh[nf][ks], acc[mr][nf], 0, 0, 0); \
            } } } }

    // prologue: x for K-step 0
    LOADX(0)

#pragma unroll 1
    for (int kk = 0; kk < 64; ++kk) {
        __syncthreads();                 // previous tile consumed
        STAGEW()                         // ga holds tile kk
        __syncthreads();                 // tile kk ready
        if (kk + 1 < 64) { LOADX(kk + 1) }   // issue next x loads (hide under MFMA)
        LOADW(kk)                        // W frags for kk (L2-hit)
        DOMFMA()
    }
#undef LOADW
#undef LOADX
#undef STAGEW
#undef DOMFMA

    // ---- epilogue: 32x32 C/D layout col=lane&31, row=(reg&3)+8*(reg>>2)+4*(lane>>5)
    // [m74/m101 HW-verified] ----
#pragma unroll
    for (int mr = 0; mr < 4; ++mr)
#pragma unroll
        for (int nf = 0; nf < 2; ++nf) {
            int ic = i0 + wn * 64 + nf * 32 + l31;
#pragma unroll
            for (int g = 0; g < 4; ++g)
#pragma unroll
                for (int q = 0; q < 4; ++q) {
                    int t = t0 + wm * 128 + mr * 32 + q + g * 8 + 4 * lhi;
                    y[((size_t)t * NB + b) * NI + ic] = acc[mr][nf][g * 4 + q];
                }
        }
}

// ---------------- BN stats pass 1: per-block partial sum/sumsq over 128 rows ----
__global__ __launch_bounds__(256) void red1(const float* __restrict__ y,
                                            float* __restrict__ part) {
    int r0 = blockIdx.x * 128;
    int c  = threadIdx.x;
    float s0 = 0.f, q0 = 0.f, s1 = 0.f, q1 = 0.f;
#pragma unroll 4
    for (int r = 0; r < 128; ++r) {
        float v0 = y[(size_t)(r0 + r) * NI + c];
        float v1 = y[(size_t)(r0 + r) * NI + c + 256];
        s0 += v0; q0 = fmaf(v0, v0, q0);
        s1 += v1; q1 = fmaf(v1, v1, q1);
    }
    part[blockIdx.x * NI + c]            = s0;
    part[blockIdx.x * NI + c + 256]      = s1;
    part[256 * NI + blockIdx.x * NI + c]       = q0;
    part[256 * NI + blockIdx.x * NI + c + 256] = q1;
}

// ---------------- BN stats pass 2: combine partials (double), emit scale/bias ----
__global__ __launch_bounds__(512) void red2(const float* __restrict__ part,
                                            const float* __restrict__ gamma,
                                            const float* __restrict__ bbeta,
                                            float* __restrict__ sb) {
    int c = threadIdx.x;
    double s = 0.0, q = 0.0;
#pragma unroll 8
    for (int p = 0; p < 256; ++p) {
        s += (double)part[p * NI + c];
        q += (double)part[256 * NI + p * NI + c];
    }
    double mean = s / 32768.0;
    double var  = q / 32768.0 - mean * mean;
    double scale = (double)gamma[c] / sqrt(var + 1e-5);
    sb[c]      = (float)scale;
    sb[NI + c] = (float)((double)bbeta[c] - mean * scale);
}

// ---------------- soft-reset LIF scan, in-place over y (=d_out) ----------------
__global__ __launch_bounds__(64) void scan_kern(float* __restrict__ y,
                                                const float* __restrict__ sb,
                                                const float* __restrict__ beta,
                                                const float* __restrict__ U0) {
    int g = blockIdx.x * 64 + threadIdx.x;   // 0..16383 = b*512 + i
    int i = g & (NI - 1);
    float scale = sb[i];
    float bias  = sb[NI + i];
    float bet = beta[i];
    float omb = 1.f - bet;
    float u = U0[g];
    float s = 0.f;
    float* yp = y + g;

    float A[32], Bv[32];
#pragma unroll
    for (int r = 0; r < 32; ++r) A[r] = yp[(size_t)r * 16384];

    for (int t0 = 0; t0 < TT; t0 += 64) {
#pragma unroll
        for (int r = 0; r < 32; ++r) Bv[r] = yp[(size_t)(t0 + 32 + r) * 16384];
#pragma unroll
        for (int r = 0; r < 32; ++r) {
            float z = fmaf(A[r], scale, bias);
            u = fmaf(bet, u - s, omb * z);
            s = (u >= 1.f) ? 1.f : 0.f;
            yp[(size_t)(t0 + r) * 16384] = s;
        }
        if (t0 + 64 < TT) {
#pragma unroll
            for (int r = 0; r < 32; ++r) A[r] = yp[(size_t)(t0 + 64 + r) * 16384];
        }
#pragma unroll
        for (int r = 0; r < 32; ++r) {
            float z = fmaf(Bv[r], scale, bias);
            u = fmaf(bet, u - s, omb * z);
            s = (u >= 1.f) ? 1.f : 0.f;
            yp[(size_t)(t0 + 32 + r) * 16384] = s;
        }
    }
}

extern "C" void kernel_launch(void* const* d_in, const int* in_sizes, int n_in,
                              void* d_out, int out_size, void* d_ws, size_t ws_size,
                              hipStream_t stream) {
    const float* x       = (const float*)d_in[0];
    const float* delay_w = (const float*)d_in[1];
    const float* delay_P = (const float*)d_in[2];
    const float* beta    = (const float*)d_in[3];
    const float* bn_g    = (const float*)d_in[4];
    const float* bn_b    = (const float*)d_in[5];
    const float* U0      = (const float*)d_in[6];
    float* y = (float*)d_out;

    // ws layout (6 MiB total, R10-proven): WF occupies [0, 6 MiB). part/sb ALIAS
    // WF's space — safe because kernels serialize on the stream and every buffer
    // is fully rewritten before each read -> deterministic under graph replay.
    short* WF   = (short*)d_ws;
    float* part = (float*)d_ws;
    float* sb   = (float*)d_ws + 2 * 256 * NI;

    dcls_kern<<<dim3(NI * NJ / 256), dim3(256), 0, stream>>>(delay_w, delay_P, WF);
    conv_mfma<<<dim3(TT / 256, NI / 256, NB), dim3(512), 0, stream>>>(x, WF, y);
    red1<<<dim3(TT * NB / 128), dim3(256), 0, stream>>>(y, part);
    red2<<<dim3(1), dim3(512), 0, stream>>>(part, bn_g, bn_b, sb);
    scan_kern<<<dim3(NB * NI / 64), dim3(64), 0, stream>>>(y, sb, beta, U0);
}

// Round 20
// 346.540 us; speedup vs baseline: 1.8118x; 1.1080x over previous
//
#include <hip/hip_runtime.h>

#define TT 1024
#define NB 32
#define NJ 128
#define NI 512
#define KD 16
#define LVL 1048576   // shorts per level in WF (512*2048)

typedef short bf16x8 __attribute__((ext_vector_type(8)));
typedef float floatx4 __attribute__((ext_vector_type(4)));

struct S3 { short h, m, l; };

// 3-way bf16 truncation split: v = h + m + l + O(2^-24 v). Residuals exact.
__device__ __forceinline__ S3 split3(float v) {
    S3 o;
    unsigned hb = __float_as_uint(v) & 0xFFFF0000u;
    float hf = __uint_as_float(hb);
    float r1 = v - hf;
    unsigned mb = __float_as_uint(r1) & 0xFFFF0000u;
    float mf = __uint_as_float(mb);
    float r2 = r1 - mf;
    unsigned lb = __float_as_uint(r2) & 0xFFFF0000u;
    o.h = (short)(hb >> 16);
    o.m = (short)(mb >> 16);
    o.l = (short)(lb >> 16);
    return o;
}

// ---------------- DCLS: W in 3-level bf16 MFMA B-frag layout [R10/R15-proven] ----------------
// k = d*128 + j. WF[lvl][ig=i>>4][ko=k>>3][c16=i&15][kq=k&7]: a wave's B-frag
// load (4 k-octets x 16 cols) is one contiguous 1KB block = 1 dwordx4/lane.
__global__ __launch_bounds__(256) void dcls_kern(const float* __restrict__ w,
                                                 const float* __restrict__ P,
                                                 short* __restrict__ WF) {
    int idx = blockIdx.x * 256 + threadIdx.x;   // idx = i*128 + j
    int j = idx & (NJ - 1);
    int i = idx >> 7;
    float wv = w[i * NJ + j];
    float c  = P[i * NJ + j] + (float)(KD / 2);
    float g[KD];
    float s = 0.f;
#pragma unroll
    for (int k = 0; k < KD; ++k) {
        float u = (float)k - c;
        g[k] = expf(-2.0f * u * u);
        s += g[k];
    }
    float inv = wv / (s + 1e-7f);
    size_t base = (size_t)(i >> 4) * 32768 + (size_t)(j >> 3) * 128 + (i & 15) * 8 + (j & 7);
#pragma unroll
    for (int d = 0; d < KD; ++d) {
        S3 sp = split3(g[(KD - 1) - d] * inv);   // conv flip
        size_t off = base + (size_t)d * 2048;
        WF[off]           = sp.h;
        WF[off + LVL]     = sp.m;
        WF[off + 2 * LVL] = sp.l;
    }
}

// ---------------- MFMA conv [R15-proven] + fused BN partial stats ----------------
// 256t x 256i tile, 512 threads = 8 waves (2 wm x 4 wn, wave-tile 128x64).
// Grid 256 = 1 block/CU single pass. XOR-swizzled A staging (split3 once per
// element, stage-side); W single-buffered from global frag layout (L2-resident).
// 6 MFMA products: AhWh + AhWm + AmWh + AmWm + AhWl + AlWh.
// NEW: epilogue reduces acc into per-(block,wm,b) channel partials (sum, sumsq)
// via shfl_xor over the kb lane-groups -> red1's 64MB re-read eliminated.
__global__ __launch_bounds__(512, 2) void conv_mfma(const float* __restrict__ x,
                                                    const short* __restrict__ WF,
                                                    float* __restrict__ y,
                                                    float* __restrict__ part) {
    __shared__ __align__(16) short PA[256][64];   // [Ah | Am], 8x16B chunks/row (32 KB)
    __shared__ __align__(16) short PL[256][64];   // [Al | --]             (32 KB)

    const int t0 = blockIdx.x * 256;
    const int i0 = blockIdx.y * 256;
    const int b  = blockIdx.z;
    const int tid = threadIdx.x;

    const int ch   = tid & 3;            // staging: 4 chunks x 8 floats = 32 cols
    const int rw   = tid >> 2;           // 0..127; thread stages rows rw, rw+128
    const int l    = tid & 63;
    const int wv   = tid >> 6;           // wave 0..7
    const int lr16 = l & 15;
    const int kb   = l >> 4;             // k-octet 0..3
    const int wm   = wv >> 2;            // 0..1 -> 128 t-rows
    const int wn   = wv & 3;             // 0..3 -> 64 i-cols

    const short* pnf[4];
#pragma unroll
    for (int nf = 0; nf < 4; ++nf) {
        int ig = (i0 + wn * 64 + nf * 16) >> 4;
        pnf[nf] = WF + (size_t)ig * 32768 + l * 8;
    }

    floatx4 acc[8][4];
#pragma unroll
    for (int mf = 0; mf < 8; ++mf)
#pragma unroll
        for (int nf = 0; nf < 4; ++nf)
#pragma unroll
            for (int e = 0; e < 4; ++e) acc[mf][nf][e] = 0.f;

    float4 ga[2][2];
    bf16x8 Wh[4], Wm[4], Wl[4];

#define LOADW(K) {                                                              \
    int koff = ((((K) >> 2) * 16 + ((K) & 3) * 4)) * 128;                       \
    _Pragma("unroll") for (int nf = 0; nf < 4; ++nf) {                          \
        const short* p = pnf[nf] + koff;                                        \
        Wh[nf] = *(const bf16x8*)(p);                                           \
        Wm[nf] = *(const bf16x8*)(p + LVL);                                     \
        Wl[nf] = *(const bf16x8*)(p + 2 * LVL); } }

#define LOADX(K) {                                                              \
    int dn = (K) >> 2, j0n = ((K) & 3) << 5;                                    \
    _Pragma("unroll") for (int s = 0; s < 2; ++s) {                             \
        int t = t0 + rw + s * 128 - dn;                                         \
        float4 z4 = make_float4(0.f, 0.f, 0.f, 0.f);                            \
        ga[s][0] = z4; ga[s][1] = z4;                                           \
        if (t >= 0) {                                                           \
            const float* ax = x + ((size_t)t * NB + b) * NJ + j0n + ch * 8;     \
            ga[s][0] = *(const float4*)ax;                                      \
            ga[s][1] = *(const float4*)(ax + 4); } } }

#define STAGEW() {                                                              \
    _Pragma("unroll") for (int s = 0; s < 2; ++s) {                             \
        int r = rw + s * 128;                                                   \
        int key = r & 7;                                                        \
        char* rowA = (char*)PA + r * 128;                                       \
        char* rowL = (char*)PL + r * 128;                                       \
        S3 a0 = split3(ga[s][0].x), a1 = split3(ga[s][0].y),                    \
           a2 = split3(ga[s][0].z), a3 = split3(ga[s][0].w),                    \
           a4 = split3(ga[s][1].x), a5 = split3(ga[s][1].y),                    \
           a6 = split3(ga[s][1].z), a7 = split3(ga[s][1].w);                    \
        bf16x8 h8, m8, l8;                                                      \
        h8[0]=a0.h; h8[1]=a1.h; h8[2]=a2.h; h8[3]=a3.h;                         \
        h8[4]=a4.h; h8[5]=a5.h; h8[6]=a6.h; h8[7]=a7.h;                         \
        m8[0]=a0.m; m8[1]=a1.m; m8[2]=a2.m; m8[3]=a3.m;                         \
        m8[4]=a4.m; m8[5]=a5.m; m8[6]=a6.m; m8[7]=a7.m;                         \
        l8[0]=a0.l; l8[1]=a1.l; l8[2]=a2.l; l8[3]=a3.l;                         \
        l8[4]=a4.l; l8[5]=a5.l; l8[6]=a6.l; l8[7]=a7.l;                         \
        *(bf16x8*)(rowA + ((ch ^ key) * 16))       = h8;                        \
        *(bf16x8*)(rowA + (((ch + 4) ^ key) * 16)) = m8;                        \
        *(bf16x8*)(rowL + ((ch ^ key) * 16))       = l8; } }

#define DOMFMA() {                                                              \
    _Pragma("unroll") for (int mf = 0; mf < 8; ++mf) {                          \
        int row = wm * 128 + mf * 16 + lr16;                                    \
        int key = row & 7;                                                      \
        const char* rowA = (const char*)PA + row * 128;                         \
        const char* rowL = (const char*)PL + row * 128;                         \
        bf16x8 ah = *(const bf16x8*)(rowA + ((kb ^ key) * 16));                 \
        bf16x8 am = *(const bf16x8*)(rowA + (((kb + 4) ^ key) * 16));           \
        bf16x8 al = *(const bf16x8*)(rowL + ((kb ^ key) * 16));                 \
        _Pragma("unroll") for (int nf = 0; nf < 4; ++nf)                        \
            acc[mf][nf] = __builtin_amdgcn_mfma_f32_16x16x32_bf16(ah, Wh[nf], acc[mf][nf], 0, 0, 0); \
        _Pragma("unroll") for (int nf = 0; nf < 4; ++nf)                        \
            acc[mf][nf] = __builtin_amdgcn_mfma_f32_16x16x32_bf16(ah, Wm[nf], acc[mf][nf], 0, 0, 0); \
        _Pragma("unroll") for (int nf = 0; nf < 4; ++nf)                        \
            acc[mf][nf] = __builtin_amdgcn_mfma_f32_16x16x32_bf16(am, Wh[nf], acc[mf][nf], 0, 0, 0); \
        _Pragma("unroll") for (int nf = 0; nf < 4; ++nf)                        \
            acc[mf][nf] = __builtin_amdgcn_mfma_f32_16x16x32_bf16(am, Wm[nf], acc[mf][nf], 0, 0, 0); \
        _Pragma("unroll") for (int nf = 0; nf < 4; ++nf)                        \
            acc[mf][nf] = __builtin_amdgcn_mfma_f32_16x16x32_bf16(ah, Wl[nf], acc[mf][nf], 0, 0, 0); \
        _Pragma("unroll") for (int nf = 0; nf < 4; ++nf)                        \
            acc[mf][nf] = __builtin_amdgcn_mfma_f32_16x16x32_bf16(al, Wh[nf], acc[mf][nf], 0, 0, 0); \
    } }

    // prologue: x for K-step 0
    LOADX(0)

#pragma unroll 1
    for (int kk = 0; kk < 64; ++kk) {
        __syncthreads();                 // previous tile consumed
        STAGEW()                         // ga holds tile kk
        __syncthreads();                 // tile kk ready
        if (kk + 1 < 64) { LOADX(kk + 1) }   // issue next x loads (hide under MFMA)
        LOADW(kk)                        // W frags for kk (L2-hit)
        DOMFMA()
    }
#undef LOADW
#undef LOADX
#undef STAGEW
#undef DOMFMA

    // ---- epilogue: y writes (C/D layout col=lane&15, row=(lane>>4)*4+reg) +
    //      fused BN partials: sum/sumsq over this wave's 128 t for each ic ----
    float ps[4], pq[4];
#pragma unroll
    for (int nf = 0; nf < 4; ++nf) { ps[nf] = 0.f; pq[nf] = 0.f; }
#pragma unroll
    for (int mf = 0; mf < 8; ++mf)
#pragma unroll
        for (int nf = 0; nf < 4; ++nf) {
            int ic = i0 + wn * 64 + nf * 16 + lr16;
#pragma unroll
            for (int q = 0; q < 4; ++q) {
                float v = acc[mf][nf][q];
                int t = t0 + wm * 128 + mf * 16 + kb * 4 + q;
                y[((size_t)t * NB + b) * NI + ic] = v;
                ps[nf] += v;
                pq[nf] = fmaf(v, v, pq[nf]);
            }
        }
    // reduce across the 4 kb lane-groups (lanes l, l^16, l^32 share lr16)
#pragma unroll
    for (int nf = 0; nf < 4; ++nf) {
        ps[nf] += __shfl_xor(ps[nf], 16, 64);
        ps[nf] += __shfl_xor(ps[nf], 32, 64);
        pq[nf] += __shfl_xor(pq[nf], 16, 64);
        pq[nf] += __shfl_xor(pq[nf], 32, 64);
    }
    if (l < 16) {
        int pi = (blockIdx.x * 2 + wm) * 32 + b;   // 0..255: (t-slice, b) partial id
#pragma unroll
        for (int nf = 0; nf < 4; ++nf) {
            int ic = i0 + wn * 64 + nf * 16 + lr16;
            part[(size_t)pi * NI + ic]            = ps[nf];
            part[(size_t)256 * NI + pi * NI + ic] = pq[nf];
        }
    }
}

// ---------------- BN stats: combine 256 partials (double), emit scale/bias ----
__global__ __launch_bounds__(512) void red2(const float* __restrict__ part,
                                            const float* __restrict__ gamma,
                                            const float* __restrict__ bbeta,
                                            float* __restrict__ sb) {
    int c = threadIdx.x;
    double s = 0.0, q = 0.0;
#pragma unroll 8
    for (int p = 0; p < 256; ++p) {
        s += (double)part[p * NI + c];
        q += (double)part[256 * NI + p * NI + c];
    }
    double mean = s / 32768.0;
    double var  = q / 32768.0 - mean * mean;
    double scale = (double)gamma[c] / sqrt(var + 1e-5);
    sb[c]      = (float)scale;
    sb[NI + c] = (float)((double)bbeta[c] - mean * scale);
}

// ---------------- soft-reset LIF scan, in-place over y (=d_out) ----------------
__global__ __launch_bounds__(64) void scan_kern(float* __restrict__ y,
                                                const float* __restrict__ sb,
                                                const float* __restrict__ beta,
                                                const float* __restrict__ U0) {
    int g = blockIdx.x * 64 + threadIdx.x;   // 0..16383 = b*512 + i
    int i = g & (NI - 1);
    float scale = sb[i];
    float bias  = sb[NI + i];
    float bet = beta[i];
    float omb = 1.f - bet;
    float u = U0[g];
    float s = 0.f;
    float* yp = y + g;

    float A[32], Bv[32];
#pragma unroll
    for (int r = 0; r < 32; ++r) A[r] = yp[(size_t)r * 16384];

    for (int t0 = 0; t0 < TT; t0 += 64) {
#pragma unroll
        for (int r = 0; r < 32; ++r) Bv[r] = yp[(size_t)(t0 + 32 + r) * 16384];
#pragma unroll
        for (int r = 0; r < 32; ++r) {
            float z = fmaf(A[r], scale, bias);
            u = fmaf(bet, u - s, omb * z);
            s = (u >= 1.f) ? 1.f : 0.f;
            yp[(size_t)(t0 + r) * 16384] = s;
        }
        if (t0 + 64 < TT) {
#pragma unroll
            for (int r = 0; r < 32; ++r) A[r] = yp[(size_t)(t0 + 64 + r) * 16384];
        }
#pragma unroll
        for (int r = 0; r < 32; ++r) {
            float z = fmaf(Bv[r], scale, bias);
            u = fmaf(bet, u - s, omb * z);
            s = (u >= 1.f) ? 1.f : 0.f;
            yp[(size_t)(t0 + 32 + r) * 16384] = s;
        }
    }
}

extern "C" void kernel_launch(void* const* d_in, const int* in_sizes, int n_in,
                              void* d_out, int out_size, void* d_ws, size_t ws_size,
                              hipStream_t stream) {
    const float* x       = (const float*)d_in[0];
    const float* delay_w = (const float*)d_in[1];
    const float* delay_P = (const float*)d_in[2];
    const float* beta    = (const float*)d_in[3];
    const float* bn_g    = (const float*)d_in[4];
    const float* bn_b    = (const float*)d_in[5];
    const float* U0      = (const float*)d_in[6];
    float* y = (float*)d_out;

    // ws layout (ws_size >= 30 MiB confirmed by R12): WF [0, 6 MiB) — read by conv
    // throughout, so partials must NOT alias it. part at +6 MiB (1 MiB: 256*512
    // sums then 256*512 sumsqs), sb at +7 MiB. Stream-serialized, every buffer
    // fully rewritten before each read -> deterministic under graph replay.
    short* WF   = (short*)d_ws;
    float* part = (float*)((char*)d_ws + (6u << 20));
    float* sb   = (float*)((char*)d_ws + (7u << 20));

    dcls_kern<<<dim3(NI * NJ / 256), dim3(256), 0, stream>>>(delay_w, delay_P, WF);
    conv_mfma<<<dim3(TT / 256, NI / 256, NB), dim3(512), 0, stream>>>(x, WF, y, part);
    red2<<<dim3(1), dim3(512), 0, stream>>>(part, bn_g, bn_b, sb);
    scan_kern<<<dim3(NB * NI / 64), dim3(64), 0, stream>>>(y, sb, beta, U0);
}

// Round 22
// 345.899 us; speedup vs baseline: 1.8152x; 1.0019x over previous
//
#include <hip/hip_runtime.h>

#define TT 1024
#define NB 32
#define NJ 128
#define NI 512
#define KD 16
#define LVL 1048576   // shorts per level in WF (512*2048)

typedef short bf16x8 __attribute__((ext_vector_type(8)));
typedef float floatx4 __attribute__((ext_vector_type(4)));

struct S3 { short h, m, l; };

// 3-way bf16 truncation split: v = h + m + l + O(2^-24 v). Residuals exact.
__device__ __forceinline__ S3 split3(float v) {
    S3 o;
    unsigned hb = __float_as_uint(v) & 0xFFFF0000u;
    float hf = __uint_as_float(hb);
    float r1 = v - hf;
    unsigned mb = __float_as_uint(r1) & 0xFFFF0000u;
    float mf = __uint_as_float(mb);
    float r2 = r1 - mf;
    unsigned lb = __float_as_uint(r2) & 0xFFFF0000u;
    o.h = (short)(hb >> 16);
    o.m = (short)(mb >> 16);
    o.l = (short)(lb >> 16);
    return o;
}

// ---------------- DCLS: W in 3-level bf16 MFMA B-frag layout [R10/R15-proven] ----------------
// k = d*128 + j. WF[lvl][ig=i>>4][ko=k>>3][c16=i&15][kq=k&7]: a wave's B-frag
// load (4 k-octets x 16 cols) is one contiguous 1KB block = 1 dwordx4/lane.
__global__ __launch_bounds__(256) void dcls_kern(const float* __restrict__ w,
                                                 const float* __restrict__ P,
                                                 short* __restrict__ WF) {
    int idx = blockIdx.x * 256 + threadIdx.x;   // idx = i*128 + j
    int j = idx & (NJ - 1);
    int i = idx >> 7;
    float wv = w[i * NJ + j];
    float c  = P[i * NJ + j] + (float)(KD / 2);
    float g[KD];
    float s = 0.f;
#pragma unroll
    for (int k = 0; k < KD; ++k) {
        float u = (float)k - c;
        g[k] = expf(-2.0f * u * u);
        s += g[k];
    }
    float inv = wv / (s + 1e-7f);
    size_t base = (size_t)(i >> 4) * 32768 + (size_t)(j >> 3) * 128 + (i & 15) * 8 + (j & 7);
#pragma unroll
    for (int d = 0; d < KD; ++d) {
        S3 sp = split3(g[(KD - 1) - d] * inv);   // conv flip
        size_t off = base + (size_t)d * 2048;
        WF[off]           = sp.h;
        WF[off + LVL]     = sp.m;
        WF[off + 2 * LVL] = sp.l;
    }
}

// ---------------- MFMA conv [R15-proven] + fused BN partial stats ----------------
// 256t x 256i tile, 512 threads = 8 waves (2 wm x 4 wn, wave-tile 128x64).
// Grid 256 = 1 block/CU single pass. XOR-swizzled A staging (split3 once per
// element, stage-side); W single-buffered from global frag layout (L2-resident).
// 6 MFMA products: AhWh + AhWm + AmWh + AmWm + AhWl + AlWh.
// Epilogue reduces acc into per-(block,wm,b) channel partials (sum, sumsq)
// via shfl_xor over the kb lane-groups -> red1's 64MB re-read eliminated.
__global__ __launch_bounds__(512, 2) void conv_mfma(const float* __restrict__ x,
                                                    const short* __restrict__ WF,
                                                    float* __restrict__ y,
                                                    float* __restrict__ part) {
    __shared__ __align__(16) short PA[256][64];   // [Ah | Am], 8x16B chunks/row (32 KB)
    __shared__ __align__(16) short PL[256][64];   // [Al | --]             (32 KB)

    const int t0 = blockIdx.x * 256;
    const int i0 = blockIdx.y * 256;
    const int b  = blockIdx.z;
    const int tid = threadIdx.x;

    const int ch   = tid & 3;            // staging: 4 chunks x 8 floats = 32 cols
    const int rw   = tid >> 2;           // 0..127; thread stages rows rw, rw+128
    const int l    = tid & 63;
    const int wv   = tid >> 6;           // wave 0..7
    const int lr16 = l & 15;
    const int kb   = l >> 4;             // k-octet 0..3
    const int wm   = wv >> 2;            // 0..1 -> 128 t-rows
    const int wn   = wv & 3;             // 0..3 -> 64 i-cols

    const short* pnf[4];
#pragma unroll
    for (int nf = 0; nf < 4; ++nf) {
        int ig = (i0 + wn * 64 + nf * 16) >> 4;
        pnf[nf] = WF + (size_t)ig * 32768 + l * 8;
    }

    floatx4 acc[8][4];
#pragma unroll
    for (int mf = 0; mf < 8; ++mf)
#pragma unroll
        for (int nf = 0; nf < 4; ++nf)
#pragma unroll
            for (int e = 0; e < 4; ++e) acc[mf][nf][e] = 0.f;

    float4 ga[2][2];
    bf16x8 Wh[4], Wm[4], Wl[4];

#define LOADW(K) {                                                              \
    int koff = ((((K) >> 2) * 16 + ((K) & 3) * 4)) * 128;                       \
    _Pragma("unroll") for (int nf = 0; nf < 4; ++nf) {                          \
        const short* p = pnf[nf] + koff;                                        \
        Wh[nf] = *(const bf16x8*)(p);                                           \
        Wm[nf] = *(const bf16x8*)(p + LVL);                                     \
        Wl[nf] = *(const bf16x8*)(p + 2 * LVL); } }

#define LOADX(K) {                                                              \
    int dn = (K) >> 2, j0n = ((K) & 3) << 5;                                    \
    _Pragma("unroll") for (int s = 0; s < 2; ++s) {                             \
        int t = t0 + rw + s * 128 - dn;                                         \
        float4 z4 = make_float4(0.f, 0.f, 0.f, 0.f);                            \
        ga[s][0] = z4; ga[s][1] = z4;                                           \
        if (t >= 0) {                                                           \
            const float* ax = x + ((size_t)t * NB + b) * NJ + j0n + ch * 8;     \
            ga[s][0] = *(const float4*)ax;                                      \
            ga[s][1] = *(const float4*)(ax + 4); } } }

#define STAGEW() {                                                              \
    _Pragma("unroll") for (int s = 0; s < 2; ++s) {                             \
        int r = rw + s * 128;                                                   \
        int key = r & 7;                                                        \
        char* rowA = (char*)PA + r * 128;                                       \
        char* rowL = (char*)PL + r * 128;                                       \
        S3 a0 = split3(ga[s][0].x), a1 = split3(ga[s][0].y),                    \
           a2 = split3(ga[s][0].z), a3 = split3(ga[s][0].w),                    \
           a4 = split3(ga[s][1].x), a5 = split3(ga[s][1].y),                    \
           a6 = split3(ga[s][1].z), a7 = split3(ga[s][1].w);                    \
        bf16x8 h8, m8, l8;                                                      \
        h8[0]=a0.h; h8[1]=a1.h; h8[2]=a2.h; h8[3]=a3.h;                         \
        h8[4]=a4.h; h8[5]=a5.h; h8[6]=a6.h; h8[7]=a7.h;                         \
        m8[0]=a0.m; m8[1]=a1.m; m8[2]=a2.m; m8[3]=a3.m;                         \
        m8[4]=a4.m; m8[5]=a5.m; m8[6]=a6.m; m8[7]=a7.m;                         \
        l8[0]=a0.l; l8[1]=a1.l; l8[2]=a2.l; l8[3]=a3.l;                         \
        l8[4]=a4.l; l8[5]=a5.l; l8[6]=a6.l; l8[7]=a7.l;                         \
        *(bf16x8*)(rowA + ((ch ^ key) * 16))       = h8;                        \
        *(bf16x8*)(rowA + (((ch + 4) ^ key) * 16)) = m8;                        \
        *(bf16x8*)(rowL + ((ch ^ key) * 16))       = l8; } }

#define DOMFMA() {                                                              \
    _Pragma("unroll") for (int mf = 0; mf < 8; ++mf) {                          \
        int row = wm * 128 + mf * 16 + lr16;                                    \
        int key = row & 7;                                                      \
        const char* rowA = (const char*)PA + row * 128;                         \
        const char* rowL = (const char*)PL + row * 128;                         \
        bf16x8 ah = *(const bf16x8*)(rowA + ((kb ^ key) * 16));                 \
        bf16x8 am = *(const bf16x8*)(rowA + (((kb + 4) ^ key) * 16));           \
        bf16x8 al = *(const bf16x8*)(rowL + ((kb ^ key) * 16));                 \
        _Pragma("unroll") for (int nf = 0; nf < 4; ++nf)                        \
            acc[mf][nf] = __builtin_amdgcn_mfma_f32_16x16x32_bf16(ah, Wh[nf], acc[mf][nf], 0, 0, 0); \
        _Pragma("unroll") for (int nf = 0; nf < 4; ++nf)                        \
            acc[mf][nf] = __builtin_amdgcn_mfma_f32_16x16x32_bf16(ah, Wm[nf], acc[mf][nf], 0, 0, 0); \
        _Pragma("unroll") for (int nf = 0; nf < 4; ++nf)                        \
            acc[mf][nf] = __builtin_amdgcn_mfma_f32_16x16x32_bf16(am, Wh[nf], acc[mf][nf], 0, 0, 0); \
        _Pragma("unroll") for (int nf = 0; nf < 4; ++nf)                        \
            acc[mf][nf] = __builtin_amdgcn_mfma_f32_16x16x32_bf16(am, Wm[nf], acc[mf][nf], 0, 0, 0); \
        _Pragma("unroll") for (int nf = 0; nf < 4; ++nf)                        \
            acc[mf][nf] = __builtin_amdgcn_mfma_f32_16x16x32_bf16(ah, Wl[nf], acc[mf][nf], 0, 0, 0); \
        _Pragma("unroll") for (int nf = 0; nf < 4; ++nf)                        \
            acc[mf][nf] = __builtin_amdgcn_mfma_f32_16x16x32_bf16(al, Wh[nf], acc[mf][nf], 0, 0, 0); \
    } }

    // prologue: x for K-step 0
    LOADX(0)

#pragma unroll 1
    for (int kk = 0; kk < 64; ++kk) {
        __syncthreads();                 // previous tile consumed
        STAGEW()                         // ga holds tile kk
        __syncthreads();                 // tile kk ready
        if (kk + 1 < 64) { LOADX(kk + 1) }   // issue next x loads (hide under MFMA)
        LOADW(kk)                        // W frags for kk (L2-hit)
        DOMFMA()
    }
#undef LOADW
#undef LOADX
#undef STAGEW
#undef DOMFMA

    // ---- epilogue: y writes (C/D layout col=lane&15, row=(lane>>4)*4+reg) +
    //      fused BN partials: sum/sumsq over this wave's 128 t for each ic ----
    float ps[4], pq[4];
#pragma unroll
    for (int nf = 0; nf < 4; ++nf) { ps[nf] = 0.f; pq[nf] = 0.f; }
#pragma unroll
    for (int mf = 0; mf < 8; ++mf)
#pragma unroll
        for (int nf = 0; nf < 4; ++nf) {
            int ic = i0 + wn * 64 + nf * 16 + lr16;
#pragma unroll
            for (int q = 0; q < 4; ++q) {
                float v = acc[mf][nf][q];
                int t = t0 + wm * 128 + mf * 16 + kb * 4 + q;
                y[((size_t)t * NB + b) * NI + ic] = v;
                ps[nf] += v;
                pq[nf] = fmaf(v, v, pq[nf]);
            }
        }
    // reduce across the 4 kb lane-groups (lanes l, l^16, l^32 share lr16)
#pragma unroll
    for (int nf = 0; nf < 4; ++nf) {
        ps[nf] += __shfl_xor(ps[nf], 16, 64);
        ps[nf] += __shfl_xor(ps[nf], 32, 64);
        pq[nf] += __shfl_xor(pq[nf], 16, 64);
        pq[nf] += __shfl_xor(pq[nf], 32, 64);
    }
    if (l < 16) {
        int pi = (blockIdx.x * 2 + wm) * 32 + b;   // 0..255: (t-slice, b) partial id
#pragma unroll
        for (int nf = 0; nf < 4; ++nf) {
            int ic = i0 + wn * 64 + nf * 16 + lr16;
            part[(size_t)pi * NI + ic]            = ps[nf];
            part[(size_t)256 * NI + pi * NI + ic] = pq[nf];
        }
    }
}

// ---------------- BN stats: combine 256 partials (double), emit scale/bias ----
__global__ __launch_bounds__(512) void red2(const float* __restrict__ part,
                                            const float* __restrict__ gamma,
                                            const float* __restrict__ bbeta,
                                            float* __restrict__ sb) {
    int c = threadIdx.x;
    double s = 0.0, q = 0.0;
#pragma unroll 8
    for (int p = 0; p < 256; ++p) {
        s += (double)part[p * NI + c];
        q += (double)part[256 * NI + p * NI + c];
    }
    double mean = s / 32768.0;
    double var  = q / 32768.0 - mean * mean;
    double scale = (double)gamma[c] / sqrt(var + 1e-5);
    sb[c]      = (float)scale;
    sb[NI + c] = (float)((double)bbeta[c] - mean * scale);
}

// ---------------- soft-reset LIF scan, in-place over y (=d_out) ----------------
__global__ __launch_bounds__(64) void scan_kern(float* __restrict__ y,
                                                const float* __restrict__ sb,
                                                const float* __restrict__ beta,
                                                const float* __restrict__ U0) {
    int g = blockIdx.x * 64 + threadIdx.x;   // 0..16383 = b*512 + i
    int i = g & (NI - 1);
    float scale = sb[i];
    float bias  = sb[NI + i];
    float bet = beta[i];
    float omb = 1.f - bet;
    float u = U0[g];
    float s = 0.f;
    float* yp = y + g;

    float A[32], Bv[32];
#pragma unroll
    for (int r = 0; r < 32; ++r) A[r] = yp[(size_t)r * 16384];

    for (int t0 = 0; t0 < TT; t0 += 64) {
#pragma unroll
        for (int r = 0; r < 32; ++r) Bv[r] = yp[(size_t)(t0 + 32 + r) * 16384];
#pragma unroll
        for (int r = 0; r < 32; ++r) {
            float z = fmaf(A[r], scale, bias);
            u = fmaf(bet, u - s, omb * z);
            s = (u >= 1.f) ? 1.f : 0.f;
            yp[(size_t)(t0 + r) * 16384] = s;
        }
        if (t0 + 64 < TT) {
#pragma unroll
            for (int r = 0; r < 32; ++r) A[r] = yp[(size_t)(t0 + 64 + r) * 16384];
        }
#pragma unroll
        for (int r = 0; r < 32; ++r) {
            float z = fmaf(Bv[r], scale, bias);
            u = fmaf(bet, u - s, omb * z);
            s = (u >= 1.f) ? 1.f : 0.f;
            yp[(size_t)(t0 + 32 + r) * 16384] = s;
        }
    }
}

extern "C" void kernel_launch(void* const* d_in, const int* in_sizes, int n_in,
                              void* d_out, int out_size, void* d_ws, size_t ws_size,
                              hipStream_t stream) {
    const float* x       = (const float*)d_in[0];
    const float* delay_w = (const float*)d_in[1];
    const float* delay_P = (const float*)d_in[2];
    const float* beta    = (const float*)d_in[3];
    const float* bn_g    = (const float*)d_in[4];
    const float* bn_b    = (const float*)d_in[5];
    const float* U0      = (const float*)d_in[6];
    float* y = (float*)d_out;

    // ws layout (ws_size >= 30 MiB confirmed by R12): WF [0, 6 MiB) — read by conv
    // throughout, so partials must NOT alias it. part at +6 MiB (1 MiB: 256*512
    // sums then 256*512 sumsqs), sb at +7 MiB. Stream-serialized, every buffer
    // fully rewritten before each read -> deterministic under graph replay.
    short* WF   = (short*)d_ws;
    float* part = (float*)((char*)d_ws + (6u << 20));
    float* sb   = (float*)((char*)d_ws + (7u << 20));

    dcls_kern<<<dim3(NI * NJ / 256), dim3(256), 0, stream>>>(delay_w, delay_P, WF);
    conv_mfma<<<dim3(TT / 256, NI / 256, NB), dim3(512), 0, stream>>>(x, WF, y, part);
    red2<<<dim3(1), dim3(512), 0, stream>>>(part, bn_g, bn_b, sb);
    scan_kern<<<dim3(NB * NI / 64), dim3(64), 0, stream>>>(y, sb, beta, U0);
}